// Round 6
// baseline (2057.089 us; speedup 1.0000x reference)
//
#include <hip/hip_runtime.h>
#include <math.h>

#define B_ 512
#define C_ 200
#define D_ 512
#define E_ 256
#define V_ 8192
#define G_ 2048
#define L_ 16

typedef __attribute__((ext_vector_type(8))) short short8;
typedef __attribute__((ext_vector_type(4))) float f32x4;

__device__ __forceinline__ float sigm(float x) { return 1.0f / (1.0f + expf(-x)); }

__device__ __forceinline__ unsigned short bf16_rn(float x) {
    unsigned int u = __float_as_uint(x);
    return (unsigned short)((u + 0x7FFFu + ((u >> 16) & 1u)) >> 16);
}
__device__ __forceinline__ float bf16f(unsigned short h) {
    return __uint_as_float(((unsigned int)h) << 16);
}

// ---------------------------------------------------------------------------
// merged setup: cvt W_proj / emb / gate-interleaved Wg + init (block ranges)
//   [0,4096)      : W_proj -> hi/lo planes
//   [4096,6144)   : emb    -> hi/lo planes
//   [6144,8704)   : Wg[2048][1280] gate-interleaved hi/lo
//   [8704,9216)   : init h0=c0=mean(valid ctx), tok0=1
// ---------------------------------------------------------------------------
__global__ __launch_bounds__(256) void k_setup(const float* __restrict__ W_proj,
                                               const float* __restrict__ emb,
                                               const float* __restrict__ W_ih,
                                               const float* __restrict__ W_hh,
                                               const float* __restrict__ ctx,
                                               const int* __restrict__ counts,
                                               unsigned short* __restrict__ Wp_hi,
                                               unsigned short* __restrict__ Wp_lo,
                                               unsigned short* __restrict__ Eb_hi,
                                               unsigned short* __restrict__ Eb_lo,
                                               unsigned short* __restrict__ Wg_hi,
                                               unsigned short* __restrict__ Wg_lo,
                                               unsigned short* __restrict__ h_hi,
                                               unsigned short* __restrict__ h_lo,
                                               float* __restrict__ c,
                                               int* __restrict__ tok) {
    int bb = blockIdx.x;
    int t = threadIdx.x;
    if (bb < 4096) {
        int i = bb * 256 + t;                       // V_*D_/4 = 1048576
        float4 v = ((const float4*)W_proj)[i];
        ushort4 h, l;
        h.x = bf16_rn(v.x); l.x = bf16_rn(v.x - bf16f(h.x));
        h.y = bf16_rn(v.y); l.y = bf16_rn(v.y - bf16f(h.y));
        h.z = bf16_rn(v.z); l.z = bf16_rn(v.z - bf16f(h.z));
        h.w = bf16_rn(v.w); l.w = bf16_rn(v.w - bf16f(h.w));
        ((ushort4*)Wp_hi)[i] = h;
        ((ushort4*)Wp_lo)[i] = l;
    } else if (bb < 6144) {
        int i = (bb - 4096) * 256 + t;              // V_*E_/4 = 524288
        float4 v = ((const float4*)emb)[i];
        ushort4 h, l;
        h.x = bf16_rn(v.x); l.x = bf16_rn(v.x - bf16f(h.x));
        h.y = bf16_rn(v.y); l.y = bf16_rn(v.y - bf16f(h.y));
        h.z = bf16_rn(v.z); l.z = bf16_rn(v.z - bf16f(h.z));
        h.w = bf16_rn(v.w); l.w = bf16_rn(v.w - bf16f(h.w));
        ((ushort4*)Eb_hi)[i] = h;
        ((ushort4*)Eb_lo)[i] = l;
    } else if (bb < 8704) {
        int idx = (bb - 6144) * 256 + t;            // 2048*320 = 655360
        int r = idx / 320;
        int k = (idx - r * 320) * 4;
        int go = ((r & 3) << 9) + (r >> 2);
        float4 v = (k < 768) ? *(const float4*)&W_ih[(size_t)go * 768 + k]
                             : *(const float4*)&W_hh[(size_t)go * 512 + (k - 768)];
        ushort4 h, l;
        h.x = bf16_rn(v.x); l.x = bf16_rn(v.x - bf16f(h.x));
        h.y = bf16_rn(v.y); l.y = bf16_rn(v.y - bf16f(h.y));
        h.z = bf16_rn(v.z); l.z = bf16_rn(v.z - bf16f(h.z));
        h.w = bf16_rn(v.w); l.w = bf16_rn(v.w - bf16f(h.w));
        *(ushort4*)&Wg_hi[(size_t)r * 1280 + k] = h;
        *(ushort4*)&Wg_lo[(size_t)r * 1280 + k] = l;
    } else {
        int b = bb - 8704;
        int cnt = counts[b];
        const float* base = ctx + (size_t)b * C_ * D_;
        float s0 = 0.f, s1 = 0.f;
        for (int cc = 0; cc < cnt; ++cc) {
            s0 += base[(size_t)cc * D_ + t];
            s1 += base[(size_t)cc * D_ + t + 256];
        }
        float inv = 1.0f / (float)cnt;
        float v0 = s0 * inv, v1 = s1 * inv;
        c[b * D_ + t] = v0;       c[b * D_ + t + 256] = v1;
        unsigned short p0 = bf16_rn(v0), p1 = bf16_rn(v1);
        h_hi[b * D_ + t] = p0;    h_hi[b * D_ + t + 256] = p1;
        h_lo[b * D_ + t] = bf16_rn(v0 - bf16f(p0));
        h_lo[b * D_ + t + 256] = bf16_rn(v1 - bf16f(p1));
        if (t == 0) tok[b] = 1;
    }
}

// ---------------------------------------------------------------------------
// fused qproj + attention. One block per batch row, 4 waves.
// Phase 0: h[b] fp32 to LDS; q[b] = h @ W_attn^T (wave per 128 cols,
//          coalesced row loads, butterfly reduce) -> q_lds.
// Phase 1: single-pass online-softmax over ctx rows (wave-strided),
//          combine waves in LDS; emit ctxv as hi/lo bf16.
// ---------------------------------------------------------------------------
__global__ __launch_bounds__(256) void k_attn(const float* __restrict__ ctx,
                                              const int* __restrict__ counts,
                                              const unsigned short* __restrict__ Hh,
                                              const unsigned short* __restrict__ Hl,
                                              const float* __restrict__ W_attn,
                                              unsigned short* __restrict__ cv_hi,
                                              unsigned short* __restrict__ cv_lo) {
    __shared__ float hf[512];
    __shared__ float q_lds[512];
    __shared__ float accw[4][512];
    __shared__ float mw_s[4], sw_s[4];
    int b = blockIdx.x;
    int t = threadIdx.x;
    int lane = t & 63;
    int wv = t >> 6;
    int cnt = counts[b];
    const float* cb = ctx + (size_t)b * C_ * D_;

    // phase 0a: reconstruct h[b] fp32 into LDS
    hf[t] = bf16f(Hh[(size_t)b * D_ + t]) + bf16f(Hl[(size_t)b * D_ + t]);
    hf[t + 256] = bf16f(Hh[(size_t)b * D_ + t + 256]) + bf16f(Hl[(size_t)b * D_ + t + 256]);
    __syncthreads();

    // phase 0b: q = h @ W_attn^T  (wave wv owns cols [wv*128, wv*128+128))
    float4 h0 = *(const float4*)&hf[lane * 8];
    float4 h1 = *(const float4*)&hf[lane * 8 + 4];
    for (int nn = wv * 128; nn < wv * 128 + 128; nn += 2) {
        const float* w0 = &W_attn[(size_t)nn * 512 + lane * 8];
        float4 wa0 = *(const float4*)(w0);
        float4 wa1 = *(const float4*)(w0 + 4);
        float4 wb0 = *(const float4*)(w0 + 512);
        float4 wb1 = *(const float4*)(w0 + 516);
        float sa = h0.x * wa0.x + h0.y * wa0.y + h0.z * wa0.z + h0.w * wa0.w +
                   h1.x * wa1.x + h1.y * wa1.y + h1.z * wa1.z + h1.w * wa1.w;
        float sb = h0.x * wb0.x + h0.y * wb0.y + h0.z * wb0.z + h0.w * wb0.w +
                   h1.x * wb1.x + h1.y * wb1.y + h1.z * wb1.z + h1.w * wb1.w;
#pragma unroll
        for (int off = 32; off; off >>= 1) {
            sa += __shfl_xor(sa, off);
            sb += __shfl_xor(sb, off);
        }
        if (lane == 0) { q_lds[nn] = sa; q_lds[nn + 1] = sb; }
    }
    __syncthreads();

    float4 q0 = *(const float4*)&q_lds[lane * 4];
    float4 q1 = *(const float4*)&q_lds[lane * 4 + 256];

    float m_w = -INFINITY, s_w = 0.f;
    float4 a0 = make_float4(0.f, 0.f, 0.f, 0.f);
    float4 a1 = make_float4(0.f, 0.f, 0.f, 0.f);

#define ATT_DOT(x0, x1) (x0.x * q0.x + x0.y * q0.y + x0.z * q0.z + x0.w * q0.w + \
                         x1.x * q1.x + x1.y * q1.y + x1.z * q1.z + x1.w * q1.w)
#define ATT_UPD(s, x0, x1)                                                     \
    {                                                                          \
        float e;                                                               \
        if (s > m_w) {                                                         \
            float sc = expf(m_w - s);                                          \
            s_w = s_w * sc + 1.f;                                              \
            a0.x *= sc; a0.y *= sc; a0.z *= sc; a0.w *= sc;                    \
            a1.x *= sc; a1.y *= sc; a1.z *= sc; a1.w *= sc;                    \
            m_w = s; e = 1.f;                                                  \
        } else {                                                               \
            e = expf(s - m_w);                                                 \
            s_w += e;                                                          \
        }                                                                      \
        a0.x += e * x0.x; a0.y += e * x0.y; a0.z += e * x0.z; a0.w += e * x0.w;\
        a1.x += e * x1.x; a1.y += e * x1.y; a1.z += e * x1.z; a1.w += e * x1.w;\
    }

    int cc = wv;
    for (; cc + 4 < cnt; cc += 8) {
        const float* rA = cb + (size_t)cc * D_;
        const float* rB = cb + (size_t)(cc + 4) * D_;
        float4 xa0 = *(const float4*)&rA[lane * 4];
        float4 xa1 = *(const float4*)&rA[lane * 4 + 256];
        float4 xb0 = *(const float4*)&rB[lane * 4];
        float4 xb1 = *(const float4*)&rB[lane * 4 + 256];
        float sa = ATT_DOT(xa0, xa1);
        float sb = ATT_DOT(xb0, xb1);
#pragma unroll
        for (int off = 32; off; off >>= 1) {
            sa += __shfl_xor(sa, off);
            sb += __shfl_xor(sb, off);
        }
        ATT_UPD(sa, xa0, xa1);
        ATT_UPD(sb, xb0, xb1);
    }
    if (cc < cnt) {
        const float* rA = cb + (size_t)cc * D_;
        float4 xa0 = *(const float4*)&rA[lane * 4];
        float4 xa1 = *(const float4*)&rA[lane * 4 + 256];
        float sa = ATT_DOT(xa0, xa1);
#pragma unroll
        for (int off = 32; off; off >>= 1) sa += __shfl_xor(sa, off);
        ATT_UPD(sa, xa0, xa1);
    }

    accw[wv][lane * 4 + 0] = a0.x; accw[wv][lane * 4 + 1] = a0.y;
    accw[wv][lane * 4 + 2] = a0.z; accw[wv][lane * 4 + 3] = a0.w;
    accw[wv][256 + lane * 4 + 0] = a1.x; accw[wv][256 + lane * 4 + 1] = a1.y;
    accw[wv][256 + lane * 4 + 2] = a1.z; accw[wv][256 + lane * 4 + 3] = a1.w;
    if (lane == 0) { mw_s[wv] = m_w; sw_s[wv] = s_w; }
    __syncthreads();

    float m_g = fmaxf(fmaxf(mw_s[0], mw_s[1]), fmaxf(mw_s[2], mw_s[3]));
    float e0 = expf(mw_s[0] - m_g), e1 = expf(mw_s[1] - m_g);
    float e2 = expf(mw_s[2] - m_g), e3 = expf(mw_s[3] - m_g);
    float inv = 1.0f / (sw_s[0] * e0 + sw_s[1] * e1 + sw_s[2] * e2 + sw_s[3] * e3);
    float v0 = (accw[0][t] * e0 + accw[1][t] * e1 + accw[2][t] * e2 + accw[3][t] * e3) * inv;
    float v1 = (accw[0][t + 256] * e0 + accw[1][t + 256] * e1 +
                accw[2][t + 256] * e2 + accw[3][t + 256] * e3) * inv;
    unsigned short p0 = bf16_rn(v0), p1 = bf16_rn(v1);
    cv_hi[(size_t)b * D_ + t] = p0;
    cv_hi[(size_t)b * D_ + t + 256] = p1;
    cv_lo[(size_t)b * D_ + t] = bf16_rn(v0 - bf16f(p0));
    cv_lo[(size_t)b * D_ + t + 256] = bf16_rn(v1 - bf16f(p1));
}

// ---------------------------------------------------------------------------
// logits = h @ W_proj^T + b_proj (split-bf16 MFMA, 64m x 128n, grid 64x8,
// XCD-strip swizzle) + per-block argmax partials (first-index tie-break).
// ---------------------------------------------------------------------------
__global__ __launch_bounds__(256, 2) void k_logits(const unsigned short* __restrict__ Ah,
                                                   const unsigned short* __restrict__ Al,
                                                   const unsigned short* __restrict__ Bh,
                                                   const unsigned short* __restrict__ Bl,
                                                   const float* __restrict__ bias,
                                                   float* __restrict__ C,
                                                   float* __restrict__ pvO,
                                                   int* __restrict__ piO) {
    __shared__ short As[8 * 512];
    __shared__ short Bs[16 * 512];
    __shared__ float pvS[64][2];
    __shared__ int piS[64][2];
    int t = threadIdx.x;
    int l = t & 63;
    int w = t >> 6;
    int wg = blockIdx.y * 64 + blockIdx.x;
    int xcd = wg & 7, lid = wg >> 3;
    int nb = xcd * 8 + (lid & 7);
    int mb = lid >> 3;
    int m0 = mb * 64;
    int n0 = nb * 128;
    int srow = l & 15;
    int koct = 8 * (l >> 4);
    int pl = w & 1;
    int mtA = w >> 1;
    const unsigned short* Apl = pl ? Al : Ah;
    const unsigned short* Bpl = pl ? Bl : Bh;
    const unsigned short* ApA = Apl + (size_t)(m0 + mtA * 16 + srow) * 512 + koct;
    const unsigned short* ApB = ApA + 32 * 512;
    const unsigned short* Bp0 = Bpl + (size_t)(n0 + (w >> 1) * 16 + srow) * 512 + koct;

    short8 rA0, rA1, rB0, rB1, rB2, rB3;
    rA0 = *(const short8*)(ApA);
    rA1 = *(const short8*)(ApB);
    rB0 = *(const short8*)(Bp0);
    rB1 = *(const short8*)(Bp0 + 32 * 512);
    rB2 = *(const short8*)(Bp0 + 64 * 512);
    rB3 = *(const short8*)(Bp0 + 96 * 512);

    f32x4 z = {0.f, 0.f, 0.f, 0.f};
    f32x4 acc[2][4];
#pragma unroll
    for (int i = 0; i < 2; ++i)
#pragma unroll
        for (int j = 0; j < 4; ++j) acc[i][j] = z;

    int wm = w >> 1, wn = w & 1;
    for (int kt = 0; kt < 512; kt += 32) {
        __syncthreads();
        *(short8*)&As[(w)*512 + l * 8] = rA0;
        *(short8*)&As[(w + 4) * 512 + l * 8] = rA1;
        *(short8*)&Bs[(w)*512 + l * 8] = rB0;
        *(short8*)&Bs[(w + 4) * 512 + l * 8] = rB1;
        *(short8*)&Bs[(w + 8) * 512 + l * 8] = rB2;
        *(short8*)&Bs[(w + 12) * 512 + l * 8] = rB3;
        __syncthreads();
        if (kt + 32 < 512) {
            rA0 = *(const short8*)(ApA + kt + 32);
            rA1 = *(const short8*)(ApB + kt + 32);
            rB0 = *(const short8*)(Bp0 + kt + 32);
            rB1 = *(const short8*)(Bp0 + 32 * 512 + kt + 32);
            rB2 = *(const short8*)(Bp0 + 64 * 512 + kt + 32);
            rB3 = *(const short8*)(Bp0 + 96 * 512 + kt + 32);
        }
        short8 ah[2], al2[2], bh[4], bl2[4];
#pragma unroll
        for (int i = 0; i < 2; ++i) {
            ah[i] = *(short8*)&As[((wm * 2 + i) * 2 + 0) * 512 + l * 8];
            al2[i] = *(short8*)&As[((wm * 2 + i) * 2 + 1) * 512 + l * 8];
        }
#pragma unroll
        for (int j = 0; j < 4; ++j) {
            bh[j] = *(short8*)&Bs[((wn * 4 + j) * 2 + 0) * 512 + l * 8];
            bl2[j] = *(short8*)&Bs[((wn * 4 + j) * 2 + 1) * 512 + l * 8];
        }
#pragma unroll
        for (int i = 0; i < 2; ++i)
#pragma unroll
            for (int j = 0; j < 4; ++j) {
                acc[i][j] = __builtin_amdgcn_mfma_f32_16x16x32_bf16(ah[i], bh[j], acc[i][j], 0, 0, 0);
                acc[i][j] = __builtin_amdgcn_mfma_f32_16x16x32_bf16(ah[i], bl2[j], acc[i][j], 0, 0, 0);
                acc[i][j] = __builtin_amdgcn_mfma_f32_16x16x32_bf16(al2[i], bh[j], acc[i][j], 0, 0, 0);
            }
    }
    int r0 = (l >> 4) * 4;
    int cl = l & 15;
    float bj_[4];
#pragma unroll
    for (int j = 0; j < 4; ++j) bj_[j] = bias[n0 + wn * 64 + j * 16 + cl];
#pragma unroll
    for (int i = 0; i < 2; ++i) {
#pragma unroll
        for (int r = 0; r < 4; ++r) {
            int row = m0 + wm * 32 + i * 16 + r0 + r;
            float bv = -INFINITY;
            int bidx = 0x7fffffff;
#pragma unroll
            for (int j = 0; j < 4; ++j) {
                int col = n0 + wn * 64 + j * 16 + cl;
                float v = acc[i][j][r] + bj_[j];
                C[(size_t)row * V_ + col] = v;
                if (v > bv) { bv = v; bidx = col; }
            }
#pragma unroll
            for (int off = 1; off < 16; off <<= 1) {
                float ov = __shfl_xor(bv, off);
                int oi = __shfl_xor(bidx, off);
                if (ov > bv || (ov == bv && oi < bidx)) { bv = ov; bidx = oi; }
            }
            if (cl == 0) {
                pvS[wm * 32 + i * 16 + r0 + r][wn] = bv;
                piS[wm * 32 + i * 16 + r0 + r][wn] = bidx;
            }
        }
    }
    __syncthreads();
    if (t < 64) {
        float v0 = pvS[t][0], v1 = pvS[t][1];
        int i0 = piS[t][0], i1 = piS[t][1];
        bool take1 = (v1 > v0);
        pvO[(size_t)(m0 + t) * 64 + nb] = take1 ? v1 : v0;
        piO[(size_t)(m0 + t) * 64 + nb] = take1 ? i1 : i0;
    }
}

// ---------------------------------------------------------------------------
// gates GEMM (split-bf16 MFMA, K=1280) + fused LSTM epilogue.
// RED=1: prologue reduces argmax partials for this block's 64 rows -> toks.
// Block 64m x 64n, 4 waves (2x2). Grid (32,8), XCD-strip swizzle.
// ---------------------------------------------------------------------------
template<int RED>
__global__ __launch_bounds__(256, 2) void k_gatesm(const int* __restrict__ tok,
                                                   const float* __restrict__ pvO,
                                                   const int* __restrict__ piO,
                                                   const unsigned short* __restrict__ Eh,
                                                   const unsigned short* __restrict__ El,
                                                   const unsigned short* __restrict__ Ch,
                                                   const unsigned short* __restrict__ Cl,
                                                   const unsigned short* __restrict__ Hh,
                                                   const unsigned short* __restrict__ Hl,
                                                   const unsigned short* __restrict__ Wh,
                                                   const unsigned short* __restrict__ Wl,
                                                   const float* __restrict__ b_ih,
                                                   const float* __restrict__ b_hh,
                                                   float* __restrict__ cbuf,
                                                   unsigned short* __restrict__ Hoh,
                                                   unsigned short* __restrict__ Hol) {
    __shared__ short As[8 * 512];
    __shared__ short Bs[8 * 512];
    __shared__ int toks[64];
    int t = threadIdx.x;
    int l = t & 63;
    int w = t >> 6;
    int wg = blockIdx.y * 32 + blockIdx.x;
    int xcd = wg & 7, lid = wg >> 3;
    int nb = xcd * 4 + (lid & 3);
    int mb = lid >> 2;
    int m0 = mb * 64;
    int n0 = nb * 64;
    int srow = l & 15;
    int koct = 8 * (l >> 4);
    int pl = w & 1;
    int mtA = w >> 1;
    int locA = mtA * 16 + srow;          // 0..31
    int rowA = m0 + locA;
    int rowB = rowA + 32;

    if (RED) {
        int ri = t >> 2, qq = t & 3;
        const float* pv = pvO + (size_t)(m0 + ri) * 64 + qq * 16;
        const int* pi = piO + (size_t)(m0 + ri) * 64 + qq * 16;
        float bv = -INFINITY;
        int bix = 0x7fffffff;
#pragma unroll
        for (int j = 0; j < 16; ++j) {
            float v = pv[j];
            int ii = pi[j];
            if (v > bv || (v == bv && ii < bix)) { bv = v; bix = ii; }
        }
#pragma unroll
        for (int off = 1; off < 4; off <<= 1) {
            float ov = __shfl_xor(bv, off);
            int oi = __shfl_xor(bix, off);
            if (ov > bv || (ov == bv && oi < bix)) { bv = ov; bix = oi; }
        }
        if (qq == 0) toks[ri] = bix;
        __syncthreads();
    }

    int tokA = RED ? toks[locA] : tok[rowA];
    int tokB = RED ? toks[locA + 32] : tok[rowB];

    const unsigned short* Ep = pl ? El : Eh;
    const unsigned short* Cp = pl ? Cl : Ch;
    const unsigned short* Hp = pl ? Hl : Hh;
    const unsigned short* Wp = pl ? Wl : Wh;
    const unsigned short* Wp0 = Wp + (size_t)(n0 + (w >> 1) * 16 + srow) * 1280 + koct;

    f32x4 z = {0.f, 0.f, 0.f, 0.f};
    f32x4 acc[2][2];
#pragma unroll
    for (int i = 0; i < 2; ++i)
#pragma unroll
        for (int j = 0; j < 2; ++j) acc[i][j] = z;

    int wm = w >> 1, wn = w & 1;
    short8 rA0, rA1, rB0, rB1;

#define GATES_LOADA(dst, row, tk, kk)                                          \
    {                                                                          \
        int kx = (kk);                                                         \
        if (kx < 256)      dst = *(const short8*)&Ep[(size_t)(tk)*256 + kx];   \
        else if (kx < 768) dst = *(const short8*)&Cp[(size_t)(row)*512 + (kx - 256)]; \
        else               dst = *(const short8*)&Hp[(size_t)(row)*512 + (kx - 768)]; \
    }

    GATES_LOADA(rA0, rowA, tokA, koct);
    GATES_LOADA(rA1, rowB, tokB, koct);
    rB0 = *(const short8*)(Wp0);
    rB1 = *(const short8*)(Wp0 + 32 * 1280);

    for (int kt = 0; kt < 1280; kt += 32) {
        __syncthreads();
        *(short8*)&As[(w)*512 + l * 8] = rA0;
        *(short8*)&As[(w + 4) * 512 + l * 8] = rA1;
        *(short8*)&Bs[(w)*512 + l * 8] = rB0;
        *(short8*)&Bs[(w + 4) * 512 + l * 8] = rB1;
        __syncthreads();
        if (kt + 32 < 1280) {
            GATES_LOADA(rA0, rowA, tokA, kt + 32 + koct);
            GATES_LOADA(rA1, rowB, tokB, kt + 32 + koct);
            rB0 = *(const short8*)(Wp0 + kt + 32);
            rB1 = *(const short8*)(Wp0 + 32 * 1280 + kt + 32);
        }
        short8 ah[2], al2[2], bh[2], bl2[2];
#pragma unroll
        for (int i = 0; i < 2; ++i) {
            ah[i] = *(short8*)&As[((wm * 2 + i) * 2 + 0) * 512 + l * 8];
            al2[i] = *(short8*)&As[((wm * 2 + i) * 2 + 1) * 512 + l * 8];
        }
#pragma unroll
        for (int j = 0; j < 2; ++j) {
            bh[j] = *(short8*)&Bs[((wn * 2 + j) * 2 + 0) * 512 + l * 8];
            bl2[j] = *(short8*)&Bs[((wn * 2 + j) * 2 + 1) * 512 + l * 8];
        }
#pragma unroll
        for (int i = 0; i < 2; ++i)
#pragma unroll
            for (int j = 0; j < 2; ++j) {
                acc[i][j] = __builtin_amdgcn_mfma_f32_16x16x32_bf16(ah[i], bh[j], acc[i][j], 0, 0, 0);
                acc[i][j] = __builtin_amdgcn_mfma_f32_16x16x32_bf16(ah[i], bl2[j], acc[i][j], 0, 0, 0);
                acc[i][j] = __builtin_amdgcn_mfma_f32_16x16x32_bf16(al2[i], bh[j], acc[i][j], 0, 0, 0);
            }
    }

    int r0 = (l >> 4) * 4;
    int cl = l & 15;
    bool act = (cl & 3) == 0;
#pragma unroll
    for (int j = 0; j < 2; ++j) {
        int gc = n0 + wn * 32 + j * 16 + cl;
        int d = gc >> 2;
        float bi_ = b_ih[d] + b_hh[d];
        float bf_ = b_ih[512 + d] + b_hh[512 + d];
        float bg_ = b_ih[1024 + d] + b_hh[1024 + d];
        float bo_ = b_ih[1536 + d] + b_hh[1536 + d];
#pragma unroll
        for (int i = 0; i < 2; ++i) {
#pragma unroll
            for (int r = 0; r < 4; ++r) {
                float x = acc[i][j][r];
                float x1 = __shfl_xor(x, 1);
                float x2 = __shfl_xor(x, 2);
                float x3 = __shfl_xor(x, 3);
                if (act) {
                    int row = m0 + wm * 32 + i * 16 + r0 + r;
                    float ig = sigm(x + bi_);
                    float fg = sigm(x1 + bf_);
                    float gg = tanhf(x2 + bg_);
                    float og = sigm(x3 + bo_);
                    float cn = fg * cbuf[(size_t)row * D_ + d] + ig * gg;
                    cbuf[(size_t)row * D_ + d] = cn;
                    float hv = og * tanhf(cn);
                    unsigned short hh = bf16_rn(hv);
                    Hoh[(size_t)row * D_ + d] = hh;
                    Hol[(size_t)row * D_ + d] = bf16_rn(hv - bf16f(hh));
                }
            }
        }
    }
}

// ---------------------------------------------------------------------------
extern "C" void kernel_launch(void* const* d_in, const int* in_sizes, int n_in,
                              void* d_out, int out_size, void* d_ws, size_t ws_size,
                              hipStream_t stream) {
    const float* ctx    = (const float*)d_in[0];
    const int*   counts = (const int*)d_in[1];
    const float* emb    = (const float*)d_in[3];
    const float* W_attn = (const float*)d_in[4];
    const float* W_ih   = (const float*)d_in[5];
    const float* b_ih   = (const float*)d_in[6];
    const float* W_hh   = (const float*)d_in[7];
    const float* b_hh   = (const float*)d_in[8];
    const float* W_proj = (const float*)d_in[9];
    const float* b_proj = (const float*)d_in[10];
    float* out = (float*)d_out;

    float* cbuf = (float*)d_ws;                 // [512][512] fp32 cell state
    unsigned short* p = (unsigned short*)(cbuf + B_ * D_);
    unsigned short* Wp_hi = p; p += (size_t)V_ * D_;
    unsigned short* Wp_lo = p; p += (size_t)V_ * D_;
    unsigned short* Eb_hi = p; p += (size_t)V_ * E_;
    unsigned short* Eb_lo = p; p += (size_t)V_ * E_;
    unsigned short* Wg_hi = p; p += (size_t)G_ * 1280;
    unsigned short* Wg_lo = p; p += (size_t)G_ * 1280;
    unsigned short* hA_hi = p; p += B_ * D_;
    unsigned short* hA_lo = p; p += B_ * D_;
    unsigned short* hB_hi = p; p += B_ * D_;
    unsigned short* hB_lo = p; p += B_ * D_;
    unsigned short* cv_hi = p; p += B_ * D_;
    unsigned short* cv_lo = p; p += B_ * D_;
    int* tok = (int*)p;                         // [512]
    float* pvO = (float*)(tok + B_);            // [512][64]
    int* piO = (int*)(pvO + B_ * 64);           // [512][64]

    k_setup<<<9216, 256, 0, stream>>>(W_proj, emb, W_ih, W_hh, ctx, counts,
                                      Wp_hi, Wp_lo, Eb_hi, Eb_lo, Wg_hi, Wg_lo,
                                      hA_hi, hA_lo, cbuf, tok);

    hipMemsetAsync(out, 0, (size_t)B_ * V_ * sizeof(float), stream);

    unsigned short *hin_hi = hA_hi, *hin_lo = hA_lo;
    unsigned short *hout_hi = hB_hi, *hout_lo = hB_lo;
    for (int t = 1; t < L_; ++t) {
        k_attn<<<B_, 256, 0, stream>>>(ctx, counts, hin_hi, hin_lo, W_attn,
                                       cv_hi, cv_lo);
        if (t == 1) {
            k_gatesm<0><<<dim3(32, 8), 256, 0, stream>>>(
                tok, pvO, piO, Eb_hi, Eb_lo, cv_hi, cv_lo, hin_hi, hin_lo,
                Wg_hi, Wg_lo, b_ih, b_hh, cbuf, hout_hi, hout_lo);
        } else {
            k_gatesm<1><<<dim3(32, 8), 256, 0, stream>>>(
                tok, pvO, piO, Eb_hi, Eb_lo, cv_hi, cv_lo, hin_hi, hin_lo,
                Wg_hi, Wg_lo, b_ih, b_hh, cbuf, hout_hi, hout_lo);
        }
        float* slab = out + (size_t)t * B_ * V_;
        k_logits<<<dim3(64, 8), 256, 0, stream>>>(hout_hi, hout_lo,
                                                  Wp_hi, Wp_lo, b_proj, slab,
                                                  pvO, piO);
        unsigned short* tmp;
        tmp = hin_hi; hin_hi = hout_hi; hout_hi = tmp;
        tmp = hin_lo; hin_lo = hout_lo; hout_lo = tmp;
    }
}

// Round 7
// 1694.698 us; speedup vs baseline: 1.2138x; 1.2138x over previous
//
#include <hip/hip_runtime.h>
#include <math.h>

#define B_ 512
#define C_ 200
#define D_ 512
#define E_ 256
#define V_ 8192
#define G_ 2048
#define L_ 16

typedef __attribute__((ext_vector_type(8))) short short8;
typedef __attribute__((ext_vector_type(4))) float f32x4;

__device__ __forceinline__ float sigm(float x) { return 1.0f / (1.0f + expf(-x)); }

__device__ __forceinline__ unsigned short bf16_rn(float x) {
    unsigned int u = __float_as_uint(x);
    return (unsigned short)((u + 0x7FFFu + ((u >> 16) & 1u)) >> 16);
}
__device__ __forceinline__ float bf16f(unsigned short h) {
    return __uint_as_float(((unsigned int)h) << 16);
}

// ---------------------------------------------------------------------------
// merged setup (block ranges):
//   [0,4096)      : W_proj -> hi/lo planes
//   [4096,6144)   : emb    -> hi/lo planes
//   [6144,8704)   : Wg[2048][1280] gate-interleaved hi/lo
//   [8704,8960)   : W_attn -> hi/lo planes
//   [8960,9472)   : init h0=c0=mean(valid ctx), tok0=1
// ---------------------------------------------------------------------------
__global__ __launch_bounds__(256) void k_setup(const float* __restrict__ W_proj,
                                               const float* __restrict__ emb,
                                               const float* __restrict__ W_ih,
                                               const float* __restrict__ W_hh,
                                               const float* __restrict__ W_attn,
                                               const float* __restrict__ ctx,
                                               const int* __restrict__ counts,
                                               unsigned short* __restrict__ Wp_hi,
                                               unsigned short* __restrict__ Wp_lo,
                                               unsigned short* __restrict__ Eb_hi,
                                               unsigned short* __restrict__ Eb_lo,
                                               unsigned short* __restrict__ Wg_hi,
                                               unsigned short* __restrict__ Wg_lo,
                                               unsigned short* __restrict__ Wa_hi,
                                               unsigned short* __restrict__ Wa_lo,
                                               unsigned short* __restrict__ h_hi,
                                               unsigned short* __restrict__ h_lo,
                                               float* __restrict__ c,
                                               int* __restrict__ tok) {
    int bb = blockIdx.x;
    int t = threadIdx.x;
    if (bb < 4096) {
        int i = bb * 256 + t;
        float4 v = ((const float4*)W_proj)[i];
        ushort4 h, l;
        h.x = bf16_rn(v.x); l.x = bf16_rn(v.x - bf16f(h.x));
        h.y = bf16_rn(v.y); l.y = bf16_rn(v.y - bf16f(h.y));
        h.z = bf16_rn(v.z); l.z = bf16_rn(v.z - bf16f(h.z));
        h.w = bf16_rn(v.w); l.w = bf16_rn(v.w - bf16f(h.w));
        ((ushort4*)Wp_hi)[i] = h;
        ((ushort4*)Wp_lo)[i] = l;
    } else if (bb < 6144) {
        int i = (bb - 4096) * 256 + t;
        float4 v = ((const float4*)emb)[i];
        ushort4 h, l;
        h.x = bf16_rn(v.x); l.x = bf16_rn(v.x - bf16f(h.x));
        h.y = bf16_rn(v.y); l.y = bf16_rn(v.y - bf16f(h.y));
        h.z = bf16_rn(v.z); l.z = bf16_rn(v.z - bf16f(h.z));
        h.w = bf16_rn(v.w); l.w = bf16_rn(v.w - bf16f(h.w));
        ((ushort4*)Eb_hi)[i] = h;
        ((ushort4*)Eb_lo)[i] = l;
    } else if (bb < 8704) {
        int idx = (bb - 6144) * 256 + t;
        int r = idx / 320;
        int k = (idx - r * 320) * 4;
        int go = ((r & 3) << 9) + (r >> 2);
        float4 v = (k < 768) ? *(const float4*)&W_ih[(size_t)go * 768 + k]
                             : *(const float4*)&W_hh[(size_t)go * 512 + (k - 768)];
        ushort4 h, l;
        h.x = bf16_rn(v.x); l.x = bf16_rn(v.x - bf16f(h.x));
        h.y = bf16_rn(v.y); l.y = bf16_rn(v.y - bf16f(h.y));
        h.z = bf16_rn(v.z); l.z = bf16_rn(v.z - bf16f(h.z));
        h.w = bf16_rn(v.w); l.w = bf16_rn(v.w - bf16f(h.w));
        *(ushort4*)&Wg_hi[(size_t)r * 1280 + k] = h;
        *(ushort4*)&Wg_lo[(size_t)r * 1280 + k] = l;
    } else if (bb < 8960) {
        int i = (bb - 8704) * 256 + t;          // D_*D_/4 = 65536
        float4 v = ((const float4*)W_attn)[i];
        ushort4 h, l;
        h.x = bf16_rn(v.x); l.x = bf16_rn(v.x - bf16f(h.x));
        h.y = bf16_rn(v.y); l.y = bf16_rn(v.y - bf16f(h.y));
        h.z = bf16_rn(v.z); l.z = bf16_rn(v.z - bf16f(h.z));
        h.w = bf16_rn(v.w); l.w = bf16_rn(v.w - bf16f(h.w));
        ((ushort4*)Wa_hi)[i] = h;
        ((ushort4*)Wa_lo)[i] = l;
    } else {
        int b = bb - 8960;
        int cnt = counts[b];
        const float* base = ctx + (size_t)b * C_ * D_;
        float s0 = 0.f, s1 = 0.f;
        for (int cc = 0; cc < cnt; ++cc) {
            s0 += base[(size_t)cc * D_ + t];
            s1 += base[(size_t)cc * D_ + t + 256];
        }
        float inv = 1.0f / (float)cnt;
        float v0 = s0 * inv, v1 = s1 * inv;
        c[b * D_ + t] = v0;       c[b * D_ + t + 256] = v1;
        unsigned short p0 = bf16_rn(v0), p1 = bf16_rn(v1);
        h_hi[b * D_ + t] = p0;    h_hi[b * D_ + t + 256] = p1;
        h_lo[b * D_ + t] = bf16_rn(v0 - bf16f(p0));
        h_lo[b * D_ + t + 256] = bf16_rn(v1 - bf16f(p1));
        if (t == 0) tok[b] = 1;
    }
}

// ---------------------------------------------------------------------------
// Shared split-bf16 GEMM body: C[64m x 128n] tile, K=512, 4 waves.
// PART=1: +bias, + per-block argmax partials (logits). PART=0: plain store.
// ---------------------------------------------------------------------------
template<int PART>
__device__ __forceinline__ void gemm_body(int nb, int mb,
                                          const unsigned short* __restrict__ Ah,
                                          const unsigned short* __restrict__ Al,
                                          const unsigned short* __restrict__ Bh,
                                          const unsigned short* __restrict__ Bl,
                                          const float* __restrict__ bias,
                                          float* __restrict__ C, int ldc,
                                          float* __restrict__ pvO,
                                          int* __restrict__ piO,
                                          short* As, short* Bs,
                                          float (*pvS)[2], int (*piS)[2]) {
    int t = threadIdx.x;
    int l = t & 63;
    int w = t >> 6;
    int m0 = mb * 64;
    int n0 = nb * 128;
    int srow = l & 15;
    int koct = 8 * (l >> 4);
    int pl = w & 1;
    int mtA = w >> 1;
    const unsigned short* Apl = pl ? Al : Ah;
    const unsigned short* Bpl = pl ? Bl : Bh;
    const unsigned short* ApA = Apl + (size_t)(m0 + mtA * 16 + srow) * 512 + koct;
    const unsigned short* ApB = ApA + 32 * 512;
    const unsigned short* Bp0 = Bpl + (size_t)(n0 + (w >> 1) * 16 + srow) * 512 + koct;

    short8 rA0, rA1, rB0, rB1, rB2, rB3;
    rA0 = *(const short8*)(ApA);
    rA1 = *(const short8*)(ApB);
    rB0 = *(const short8*)(Bp0);
    rB1 = *(const short8*)(Bp0 + 32 * 512);
    rB2 = *(const short8*)(Bp0 + 64 * 512);
    rB3 = *(const short8*)(Bp0 + 96 * 512);

    f32x4 z = {0.f, 0.f, 0.f, 0.f};
    f32x4 acc[2][4];
#pragma unroll
    for (int i = 0; i < 2; ++i)
#pragma unroll
        for (int j = 0; j < 4; ++j) acc[i][j] = z;

    int wm = w >> 1, wn = w & 1;
    for (int kt = 0; kt < 512; kt += 32) {
        __syncthreads();
        *(short8*)&As[(w)*512 + l * 8] = rA0;
        *(short8*)&As[(w + 4) * 512 + l * 8] = rA1;
        *(short8*)&Bs[(w)*512 + l * 8] = rB0;
        *(short8*)&Bs[(w + 4) * 512 + l * 8] = rB1;
        *(short8*)&Bs[(w + 8) * 512 + l * 8] = rB2;
        *(short8*)&Bs[(w + 12) * 512 + l * 8] = rB3;
        __syncthreads();
        if (kt + 32 < 512) {
            rA0 = *(const short8*)(ApA + kt + 32);
            rA1 = *(const short8*)(ApB + kt + 32);
            rB0 = *(const short8*)(Bp0 + kt + 32);
            rB1 = *(const short8*)(Bp0 + 32 * 512 + kt + 32);
            rB2 = *(const short8*)(Bp0 + 64 * 512 + kt + 32);
            rB3 = *(const short8*)(Bp0 + 96 * 512 + kt + 32);
        }
        short8 ah[2], al2[2], bh[4], bl2[4];
#pragma unroll
        for (int i = 0; i < 2; ++i) {
            ah[i] = *(short8*)&As[((wm * 2 + i) * 2 + 0) * 512 + l * 8];
            al2[i] = *(short8*)&As[((wm * 2 + i) * 2 + 1) * 512 + l * 8];
        }
#pragma unroll
        for (int j = 0; j < 4; ++j) {
            bh[j] = *(short8*)&Bs[((wn * 4 + j) * 2 + 0) * 512 + l * 8];
            bl2[j] = *(short8*)&Bs[((wn * 4 + j) * 2 + 1) * 512 + l * 8];
        }
#pragma unroll
        for (int i = 0; i < 2; ++i)
#pragma unroll
            for (int j = 0; j < 4; ++j) {
                acc[i][j] = __builtin_amdgcn_mfma_f32_16x16x32_bf16(ah[i], bh[j], acc[i][j], 0, 0, 0);
                acc[i][j] = __builtin_amdgcn_mfma_f32_16x16x32_bf16(ah[i], bl2[j], acc[i][j], 0, 0, 0);
                acc[i][j] = __builtin_amdgcn_mfma_f32_16x16x32_bf16(al2[i], bh[j], acc[i][j], 0, 0, 0);
            }
    }
    int r0 = (l >> 4) * 4;
    int cl = l & 15;
    if (PART) {
        float bj_[4];
#pragma unroll
        for (int j = 0; j < 4; ++j) bj_[j] = bias[n0 + wn * 64 + j * 16 + cl];
#pragma unroll
        for (int i = 0; i < 2; ++i) {
#pragma unroll
            for (int r = 0; r < 4; ++r) {
                int row = m0 + wm * 32 + i * 16 + r0 + r;
                float bv = -INFINITY;
                int bidx = 0x7fffffff;
#pragma unroll
                for (int j = 0; j < 4; ++j) {
                    int col = n0 + wn * 64 + j * 16 + cl;
                    float v = acc[i][j][r] + bj_[j];
                    C[(size_t)row * ldc + col] = v;
                    if (v > bv) { bv = v; bidx = col; }
                }
#pragma unroll
                for (int off = 1; off < 16; off <<= 1) {
                    float ov = __shfl_xor(bv, off);
                    int oi = __shfl_xor(bidx, off);
                    if (ov > bv || (ov == bv && oi < bidx)) { bv = ov; bidx = oi; }
                }
                if (cl == 0) {
                    pvS[wm * 32 + i * 16 + r0 + r][wn] = bv;
                    piS[wm * 32 + i * 16 + r0 + r][wn] = bidx;
                }
            }
        }
        __syncthreads();
        if (t < 64) {
            float v0 = pvS[t][0], v1 = pvS[t][1];
            int i0 = piS[t][0], i1 = piS[t][1];
            bool take1 = (v1 > v0);
            pvO[(size_t)(m0 + t) * 64 + nb] = take1 ? v1 : v0;
            piO[(size_t)(m0 + t) * 64 + nb] = take1 ? i1 : i0;
        }
    } else {
#pragma unroll
        for (int i = 0; i < 2; ++i)
#pragma unroll
            for (int j = 0; j < 4; ++j) {
                int col = n0 + wn * 64 + j * 16 + cl;
                int rowb = m0 + wm * 32 + i * 16 + r0;
#pragma unroll
                for (int r = 0; r < 4; ++r)
                    C[(size_t)(rowb + r) * ldc + col] = acc[i][j][r];
            }
    }
}

// ---------------------------------------------------------------------------
// mega: blocks [0,512) = logits(h) w/ XCD swizzle + argmax partials;
//       blocks [512,544) = qproj(h) -> qbuf (next step's q).
// ---------------------------------------------------------------------------
__global__ __launch_bounds__(256, 2) void k_mega(const unsigned short* __restrict__ Ah,
                                                 const unsigned short* __restrict__ Al,
                                                 const unsigned short* __restrict__ Wph,
                                                 const unsigned short* __restrict__ Wpl,
                                                 const float* __restrict__ bias,
                                                 float* __restrict__ Cl_,
                                                 float* __restrict__ pvO,
                                                 int* __restrict__ piO,
                                                 const unsigned short* __restrict__ Wah,
                                                 const unsigned short* __restrict__ Wal,
                                                 float* __restrict__ qbuf) {
    __shared__ short As[8 * 512];
    __shared__ short Bs[16 * 512];
    __shared__ float pvS[64][2];
    __shared__ int piS[64][2];
    int bb = blockIdx.x;
    if (bb < 512) {
        int xcd = bb & 7, lid = bb >> 3;
        int nb = xcd * 8 + (lid & 7);
        int mb = lid >> 3;
        gemm_body<1>(nb, mb, Ah, Al, Wph, Wpl, bias, Cl_, V_, pvO, piO,
                     As, Bs, pvS, piS);
    } else {
        int idx = bb - 512;
        int nb = idx & 3, mb = idx >> 2;
        gemm_body<0>(nb, mb, Ah, Al, Wah, Wal, nullptr, qbuf, D_, nullptr, nullptr,
                     As, Bs, pvS, piS);
    }
}

// standalone qproj for the first step (h0)
__global__ __launch_bounds__(256, 2) void k_qproj(const unsigned short* __restrict__ Ah,
                                                  const unsigned short* __restrict__ Al,
                                                  const unsigned short* __restrict__ Wah,
                                                  const unsigned short* __restrict__ Wal,
                                                  float* __restrict__ qbuf) {
    __shared__ short As[8 * 512];
    __shared__ short Bs[16 * 512];
    __shared__ float pvS[64][2];
    __shared__ int piS[64][2];
    int nb = blockIdx.x & 3, mb = blockIdx.x >> 2;
    gemm_body<0>(nb, mb, Ah, Al, Wah, Wal, nullptr, qbuf, D_, nullptr, nullptr,
                 As, Bs, pvS, piS);
}

// ---------------------------------------------------------------------------
// attention: single-pass online softmax. One block per batch row, 4 waves.
// ---------------------------------------------------------------------------
__global__ __launch_bounds__(256) void k_attn(const float* __restrict__ ctx,
                                              const int* __restrict__ counts,
                                              const float* __restrict__ q,
                                              unsigned short* __restrict__ cv_hi,
                                              unsigned short* __restrict__ cv_lo) {
    __shared__ float accw[4][512];
    __shared__ float mw_s[4], sw_s[4];
    int b = blockIdx.x;
    int t = threadIdx.x;
    int lane = t & 63;
    int wv = t >> 6;
    int cnt = counts[b];
    const float* cb = ctx + (size_t)b * C_ * D_;

    float4 q0 = *(const float4*)&q[(size_t)b * D_ + lane * 4];
    float4 q1 = *(const float4*)&q[(size_t)b * D_ + lane * 4 + 256];

    float m_w = -INFINITY, s_w = 0.f;
    float4 a0 = make_float4(0.f, 0.f, 0.f, 0.f);
    float4 a1 = make_float4(0.f, 0.f, 0.f, 0.f);

#define ATT_DOT(x0, x1) (x0.x * q0.x + x0.y * q0.y + x0.z * q0.z + x0.w * q0.w + \
                         x1.x * q1.x + x1.y * q1.y + x1.z * q1.z + x1.w * q1.w)
#define ATT_UPD(s, x0, x1)                                                     \
    {                                                                          \
        float e;                                                               \
        if (s > m_w) {                                                         \
            float sc = expf(m_w - s);                                          \
            s_w = s_w * sc + 1.f;                                              \
            a0.x *= sc; a0.y *= sc; a0.z *= sc; a0.w *= sc;                    \
            a1.x *= sc; a1.y *= sc; a1.z *= sc; a1.w *= sc;                    \
            m_w = s; e = 1.f;                                                  \
        } else {                                                               \
            e = expf(s - m_w);                                                 \
            s_w += e;                                                          \
        }                                                                      \
        a0.x += e * x0.x; a0.y += e * x0.y; a0.z += e * x0.z; a0.w += e * x0.w;\
        a1.x += e * x1.x; a1.y += e * x1.y; a1.z += e * x1.z; a1.w += e * x1.w;\
    }

    int cc = wv;
    for (; cc + 4 < cnt; cc += 8) {
        const float* rA = cb + (size_t)cc * D_;
        const float* rB = cb + (size_t)(cc + 4) * D_;
        float4 xa0 = *(const float4*)&rA[lane * 4];
        float4 xa1 = *(const float4*)&rA[lane * 4 + 256];
        float4 xb0 = *(const float4*)&rB[lane * 4];
        float4 xb1 = *(const float4*)&rB[lane * 4 + 256];
        float sa = ATT_DOT(xa0, xa1);
        float sb = ATT_DOT(xb0, xb1);
#pragma unroll
        for (int off = 32; off; off >>= 1) {
            sa += __shfl_xor(sa, off);
            sb += __shfl_xor(sb, off);
        }
        ATT_UPD(sa, xa0, xa1);
        ATT_UPD(sb, xb0, xb1);
    }
    if (cc < cnt) {
        const float* rA = cb + (size_t)cc * D_;
        float4 xa0 = *(const float4*)&rA[lane * 4];
        float4 xa1 = *(const float4*)&rA[lane * 4 + 256];
        float sa = ATT_DOT(xa0, xa1);
#pragma unroll
        for (int off = 32; off; off >>= 1) sa += __shfl_xor(sa, off);
        ATT_UPD(sa, xa0, xa1);
    }

    accw[wv][lane * 4 + 0] = a0.x; accw[wv][lane * 4 + 1] = a0.y;
    accw[wv][lane * 4 + 2] = a0.z; accw[wv][lane * 4 + 3] = a0.w;
    accw[wv][256 + lane * 4 + 0] = a1.x; accw[wv][256 + lane * 4 + 1] = a1.y;
    accw[wv][256 + lane * 4 + 2] = a1.z; accw[wv][256 + lane * 4 + 3] = a1.w;
    if (lane == 0) { mw_s[wv] = m_w; sw_s[wv] = s_w; }
    __syncthreads();

    float m_g = fmaxf(fmaxf(mw_s[0], mw_s[1]), fmaxf(mw_s[2], mw_s[3]));
    float e0 = expf(mw_s[0] - m_g), e1 = expf(mw_s[1] - m_g);
    float e2 = expf(mw_s[2] - m_g), e3 = expf(mw_s[3] - m_g);
    float inv = 1.0f / (sw_s[0] * e0 + sw_s[1] * e1 + sw_s[2] * e2 + sw_s[3] * e3);
    float v0 = (accw[0][t] * e0 + accw[1][t] * e1 + accw[2][t] * e2 + accw[3][t] * e3) * inv;
    float v1 = (accw[0][t + 256] * e0 + accw[1][t + 256] * e1 +
                accw[2][t + 256] * e2 + accw[3][t + 256] * e3) * inv;
    unsigned short p0 = bf16_rn(v0), p1 = bf16_rn(v1);
    cv_hi[(size_t)b * D_ + t] = p0;
    cv_hi[(size_t)b * D_ + t + 256] = p1;
    cv_lo[(size_t)b * D_ + t] = bf16_rn(v0 - bf16f(p0));
    cv_lo[(size_t)b * D_ + t + 256] = bf16_rn(v1 - bf16f(p1));
}

// ---------------------------------------------------------------------------
// gates GEMM (split-bf16 MFMA, K=1280) + fused LSTM epilogue.
// RED=1: prologue reduces argmax partials for this block's 64 rows -> toks.
// ---------------------------------------------------------------------------
template<int RED>
__global__ __launch_bounds__(256, 2) void k_gatesm(const int* __restrict__ tok,
                                                   const float* __restrict__ pvO,
                                                   const int* __restrict__ piO,
                                                   const unsigned short* __restrict__ Eh,
                                                   const unsigned short* __restrict__ El,
                                                   const unsigned short* __restrict__ Ch,
                                                   const unsigned short* __restrict__ Cl,
                                                   const unsigned short* __restrict__ Hh,
                                                   const unsigned short* __restrict__ Hl,
                                                   const unsigned short* __restrict__ Wh,
                                                   const unsigned short* __restrict__ Wl,
                                                   const float* __restrict__ b_ih,
                                                   const float* __restrict__ b_hh,
                                                   float* __restrict__ cbuf,
                                                   unsigned short* __restrict__ Hoh,
                                                   unsigned short* __restrict__ Hol) {
    __shared__ short As[8 * 512];
    __shared__ short Bs[8 * 512];
    __shared__ int toks[64];
    int t = threadIdx.x;
    int l = t & 63;
    int w = t >> 6;
    int wg = blockIdx.y * 32 + blockIdx.x;
    int xcd = wg & 7, lid = wg >> 3;
    int nb = xcd * 4 + (lid & 3);
    int mb = lid >> 2;
    int m0 = mb * 64;
    int n0 = nb * 64;
    int srow = l & 15;
    int koct = 8 * (l >> 4);
    int pl = w & 1;
    int mtA = w >> 1;
    int locA = mtA * 16 + srow;
    int rowA = m0 + locA;
    int rowB = rowA + 32;

    if (RED) {
        int ri = t >> 2, qq = t & 3;
        const float* pv = pvO + (size_t)(m0 + ri) * 64 + qq * 16;
        const int* pi = piO + (size_t)(m0 + ri) * 64 + qq * 16;
        float bv = -INFINITY;
        int bix = 0x7fffffff;
#pragma unroll
        for (int j = 0; j < 16; ++j) {
            float v = pv[j];
            int ii = pi[j];
            if (v > bv || (v == bv && ii < bix)) { bv = v; bix = ii; }
        }
#pragma unroll
        for (int off = 1; off < 4; off <<= 1) {
            float ov = __shfl_xor(bv, off);
            int oi = __shfl_xor(bix, off);
            if (ov > bv || (ov == bv && oi < bix)) { bv = ov; bix = oi; }
        }
        if (qq == 0) toks[ri] = bix;
        __syncthreads();
    }

    int tokA = RED ? toks[locA] : tok[rowA];
    int tokB = RED ? toks[locA + 32] : tok[rowB];

    const unsigned short* Ep = pl ? El : Eh;
    const unsigned short* Cp = pl ? Cl : Ch;
    const unsigned short* Hp = pl ? Hl : Hh;
    const unsigned short* Wp = pl ? Wl : Wh;
    const unsigned short* Wp0 = Wp + (size_t)(n0 + (w >> 1) * 16 + srow) * 1280 + koct;

    f32x4 z = {0.f, 0.f, 0.f, 0.f};
    f32x4 acc[2][2];
#pragma unroll
    for (int i = 0; i < 2; ++i)
#pragma unroll
        for (int j = 0; j < 2; ++j) acc[i][j] = z;

    int wm = w >> 1, wn = w & 1;
    short8 rA0, rA1, rB0, rB1;

#define GATES_LOADA(dst, row, tk, kk)                                          \
    {                                                                          \
        int kx = (kk);                                                         \
        if (kx < 256)      dst = *(const short8*)&Ep[(size_t)(tk)*256 + kx];   \
        else if (kx < 768) dst = *(const short8*)&Cp[(size_t)(row)*512 + (kx - 256)]; \
        else               dst = *(const short8*)&Hp[(size_t)(row)*512 + (kx - 768)]; \
    }

    GATES_LOADA(rA0, rowA, tokA, koct);
    GATES_LOADA(rA1, rowB, tokB, koct);
    rB0 = *(const short8*)(Wp0);
    rB1 = *(const short8*)(Wp0 + 32 * 1280);

    for (int kt = 0; kt < 1280; kt += 32) {
        __syncthreads();
        *(short8*)&As[(w)*512 + l * 8] = rA0;
        *(short8*)&As[(w + 4) * 512 + l * 8] = rA1;
        *(short8*)&Bs[(w)*512 + l * 8] = rB0;
        *(short8*)&Bs[(w + 4) * 512 + l * 8] = rB1;
        __syncthreads();
        if (kt + 32 < 1280) {
            GATES_LOADA(rA0, rowA, tokA, kt + 32 + koct);
            GATES_LOADA(rA1, rowB, tokB, kt + 32 + koct);
            rB0 = *(const short8*)(Wp0 + kt + 32);
            rB1 = *(const short8*)(Wp0 + 32 * 1280 + kt + 32);
        }
        short8 ah[2], al2[2], bh[2], bl2[2];
#pragma unroll
        for (int i = 0; i < 2; ++i) {
            ah[i] = *(short8*)&As[((wm * 2 + i) * 2 + 0) * 512 + l * 8];
            al2[i] = *(short8*)&As[((wm * 2 + i) * 2 + 1) * 512 + l * 8];
        }
#pragma unroll
        for (int j = 0; j < 2; ++j) {
            bh[j] = *(short8*)&Bs[((wn * 2 + j) * 2 + 0) * 512 + l * 8];
            bl2[j] = *(short8*)&Bs[((wn * 2 + j) * 2 + 1) * 512 + l * 8];
        }
#pragma unroll
        for (int i = 0; i < 2; ++i)
#pragma unroll
            for (int j = 0; j < 2; ++j) {
                acc[i][j] = __builtin_amdgcn_mfma_f32_16x16x32_bf16(ah[i], bh[j], acc[i][j], 0, 0, 0);
                acc[i][j] = __builtin_amdgcn_mfma_f32_16x16x32_bf16(ah[i], bl2[j], acc[i][j], 0, 0, 0);
                acc[i][j] = __builtin_amdgcn_mfma_f32_16x16x32_bf16(al2[i], bh[j], acc[i][j], 0, 0, 0);
            }
    }

    int r0 = (l >> 4) * 4;
    int cl = l & 15;
    bool act = (cl & 3) == 0;
#pragma unroll
    for (int j = 0; j < 2; ++j) {
        int gc = n0 + wn * 32 + j * 16 + cl;
        int d = gc >> 2;
        float bi_ = b_ih[d] + b_hh[d];
        float bf_ = b_ih[512 + d] + b_hh[512 + d];
        float bg_ = b_ih[1024 + d] + b_hh[1024 + d];
        float bo_ = b_ih[1536 + d] + b_hh[1536 + d];
#pragma unroll
        for (int i = 0; i < 2; ++i) {
#pragma unroll
            for (int r = 0; r < 4; ++r) {
                float x = acc[i][j][r];
                float x1 = __shfl_xor(x, 1);
                float x2 = __shfl_xor(x, 2);
                float x3 = __shfl_xor(x, 3);
                if (act) {
                    int row = m0 + wm * 32 + i * 16 + r0 + r;
                    float ig = sigm(x + bi_);
                    float fg = sigm(x1 + bf_);
                    float gg = tanhf(x2 + bg_);
                    float og = sigm(x3 + bo_);
                    float cn = fg * cbuf[(size_t)row * D_ + d] + ig * gg;
                    cbuf[(size_t)row * D_ + d] = cn;
                    float hv = og * tanhf(cn);
                    unsigned short hh = bf16_rn(hv);
                    Hoh[(size_t)row * D_ + d] = hh;
                    Hol[(size_t)row * D_ + d] = bf16_rn(hv - bf16f(hh));
                }
            }
        }
    }
}

// ---------------------------------------------------------------------------
extern "C" void kernel_launch(void* const* d_in, const int* in_sizes, int n_in,
                              void* d_out, int out_size, void* d_ws, size_t ws_size,
                              hipStream_t stream) {
    const float* ctx    = (const float*)d_in[0];
    const int*   counts = (const int*)d_in[1];
    const float* emb    = (const float*)d_in[3];
    const float* W_attn = (const float*)d_in[4];
    const float* W_ih   = (const float*)d_in[5];
    const float* b_ih   = (const float*)d_in[6];
    const float* W_hh   = (const float*)d_in[7];
    const float* b_hh   = (const float*)d_in[8];
    const float* W_proj = (const float*)d_in[9];
    const float* b_proj = (const float*)d_in[10];
    float* out = (float*)d_out;

    float* qbuf = (float*)d_ws;                 // [512][512]
    float* cbuf = qbuf + B_ * D_;               // [512][512]
    unsigned short* p = (unsigned short*)(cbuf + B_ * D_);
    unsigned short* Wa_hi = p; p += D_ * D_;
    unsigned short* Wa_lo = p; p += D_ * D_;
    unsigned short* Wp_hi = p; p += (size_t)V_ * D_;
    unsigned short* Wp_lo = p; p += (size_t)V_ * D_;
    unsigned short* Eb_hi = p; p += (size_t)V_ * E_;
    unsigned short* Eb_lo = p; p += (size_t)V_ * E_;
    unsigned short* Wg_hi = p; p += (size_t)G_ * 1280;
    unsigned short* Wg_lo = p; p += (size_t)G_ * 1280;
    unsigned short* hA_hi = p; p += B_ * D_;
    unsigned short* hA_lo = p; p += B_ * D_;
    unsigned short* hB_hi = p; p += B_ * D_;
    unsigned short* hB_lo = p; p += B_ * D_;
    unsigned short* cv_hi = p; p += B_ * D_;
    unsigned short* cv_lo = p; p += B_ * D_;
    int* tok = (int*)p;                         // [512]
    float* pvO = (float*)(tok + B_);            // [512][64]
    int* piO = (int*)(pvO + B_ * 64);           // [512][64]

    k_setup<<<9472, 256, 0, stream>>>(W_proj, emb, W_ih, W_hh, W_attn, ctx, counts,
                                      Wp_hi, Wp_lo, Eb_hi, Eb_lo, Wg_hi, Wg_lo,
                                      Wa_hi, Wa_lo, hA_hi, hA_lo, cbuf, tok);

    hipMemsetAsync(out, 0, (size_t)B_ * V_ * sizeof(float), stream);

    // q for step 1 from h0
    k_qproj<<<32, 256, 0, stream>>>(hA_hi, hA_lo, Wa_hi, Wa_lo, qbuf);

    unsigned short *hin_hi = hA_hi, *hin_lo = hA_lo;
    unsigned short *hout_hi = hB_hi, *hout_lo = hB_lo;
    for (int t = 1; t < L_; ++t) {
        k_attn<<<B_, 256, 0, stream>>>(ctx, counts, qbuf, cv_hi, cv_lo);
        if (t == 1) {
            k_gatesm<0><<<dim3(32, 8), 256, 0, stream>>>(
                tok, pvO, piO, Eb_hi, Eb_lo, cv_hi, cv_lo, hin_hi, hin_lo,
                Wg_hi, Wg_lo, b_ih, b_hh, cbuf, hout_hi, hout_lo);
        } else {
            k_gatesm<1><<<dim3(32, 8), 256, 0, stream>>>(
                tok, pvO, piO, Eb_hi, Eb_lo, cv_hi, cv_lo, hin_hi, hin_lo,
                Wg_hi, Wg_lo, b_ih, b_hh, cbuf, hout_hi, hout_lo);
        }
        float* slab = out + (size_t)t * B_ * V_;
        k_mega<<<544, 256, 0, stream>>>(hout_hi, hout_lo, Wp_hi, Wp_lo, b_proj,
                                        slab, pvO, piO, Wa_hi, Wa_lo, qbuf);
        unsigned short* tmp;
        tmp = hin_hi; hin_hi = hout_hi; hout_hi = tmp;
        tmp = hin_lo; hin_lo = hout_lo; hout_lo = tmp;
    }
}